// Round 1
// baseline (240.658 us; speedup 1.0000x reference)
//
#include <hip/hip_runtime.h>

// PatchExpand(dim=256) + rearrange + LayerNorm(128), fused.
// x1:[16,4096,256]f32  W:[512,256]f32  gamma,beta:[128]f32 -> out:[16,16384,128]f32
// GEMM M=65536 N=512 K=256 in bf16 MFMA (threshold 0.106 allows it), LN fused in epilogue.

typedef __attribute__((ext_vector_type(8))) short bf16x8;
typedef __attribute__((ext_vector_type(4))) float f32x4;

__device__ __forceinline__ unsigned short f2bf(float f) {
    unsigned u = __builtin_bit_cast(unsigned, f);
    u += 0x7fffu + ((u >> 16) & 1u);   // round-to-nearest-even (inputs are finite randoms)
    return (unsigned short)(u >> 16);
}

#define KPITCH 72   // 64 bf16 K-chunk + 8 pad: rows 16B-aligned, worst 2-way bank alias (free)

__global__ __launch_bounds__(512, 1)
void fused_expand_ln(const float* __restrict__ x1,
                     const float* __restrict__ Wg,
                     const float* __restrict__ gamma,
                     const float* __restrict__ beta,
                     float* __restrict__ out) {
    __shared__ unsigned short Alds[128 * KPITCH];   // 18 KiB
    __shared__ unsigned short Wlds[512 * KPITCH];   // 72 KiB

    const int tid  = threadIdx.x;
    const int l0   = blockIdx.x * 128;          // first M-row of this block
    const int wid  = tid >> 6;
    const int lane = tid & 63;
    const int wm   = wid >> 2;                  // 0..1 : M half (64 rows)
    const int wn   = wid & 3;                   // 0..3 : N chunk of 128 == LN group == p
    const int g    = lane >> 4;                 // 0..3
    const int c    = lane & 15;

    f32x4 acc[4][8];
#pragma unroll
    for (int i = 0; i < 4; ++i)
#pragma unroll
        for (int j = 0; j < 8; ++j) acc[i][j] = (f32x4){0.f, 0.f, 0.f, 0.f};

    const float4* x4 = reinterpret_cast<const float4*>(x1);
    const float4* w4 = reinterpret_cast<const float4*>(Wg);

    for (int kc = 0; kc < 4; ++kc) {
        const int kk4 = kc * 16;                // K-chunk offset in float4 units
        // stage A chunk: 128 rows x 64 k  (2048 float4, 4/thread, coalesced)
#pragma unroll
        for (int j = 0; j < 4; ++j) {
            int fidx = tid + j * 512;
            int row = fidx >> 4, kq = fidx & 15;
            float4 v = x4[(size_t)(l0 + row) * 64 + kk4 + kq];
            ushort4 o = { f2bf(v.x), f2bf(v.y), f2bf(v.z), f2bf(v.w) };
            *reinterpret_cast<ushort4*>(&Alds[row * KPITCH + kq * 4]) = o;
        }
        // stage W chunk: 512 rows x 64 k  (8192 float4, 16/thread)
#pragma unroll
        for (int j = 0; j < 16; ++j) {
            int fidx = tid + j * 512;
            int row = fidx >> 4, kq = fidx & 15;
            float4 v = w4[(size_t)row * 64 + kk4 + kq];
            ushort4 o = { f2bf(v.x), f2bf(v.y), f2bf(v.z), f2bf(v.w) };
            *reinterpret_cast<ushort4*>(&Wlds[row * KPITCH + kq * 4]) = o;
        }
        __syncthreads();
#pragma unroll
        for (int ks = 0; ks < 2; ++ks) {
            const int koff = ks * 32 + g * 8;
            bf16x8 a[4], b[8];
#pragma unroll
            for (int mi = 0; mi < 4; ++mi)
                a[mi] = *reinterpret_cast<const bf16x8*>(
                    &Alds[(wm * 64 + mi * 16 + c) * KPITCH + koff]);
#pragma unroll
            for (int ni = 0; ni < 8; ++ni)
                b[ni] = *reinterpret_cast<const bf16x8*>(
                    &Wlds[(wn * 128 + ni * 16 + c) * KPITCH + koff]);
#pragma unroll
            for (int mi = 0; mi < 4; ++mi)
#pragma unroll
                for (int ni = 0; ni < 8; ++ni)
                    acc[mi][ni] = __builtin_amdgcn_mfma_f32_16x16x32_bf16(
                        a[mi], b[ni], acc[mi][ni], 0, 0, 0);
        }
        __syncthreads();
    }

    // ---- fused epilogue: LayerNorm over each 128-col chunk, scattered write ----
    const int b  = l0 >> 12;                    // batch
    const int h0 = (l0 & 4095) >> 6;            // first h of tile (even)
    const int p1 = wn >> 1, p2 = wn & 1;

    float gam[8], bet[8];
#pragma unroll
    for (int ni = 0; ni < 8; ++ni) {
        gam[ni] = gamma[ni * 16 + c];
        bet[ni] = beta[ni * 16 + c];
    }

    float* outp = out + (size_t)b * (16384 * 128);

#pragma unroll
    for (int mi = 0; mi < 4; ++mi) {
#pragma unroll
        for (int r = 0; r < 4; ++r) {
            // row-local stats: 8 in-lane values, then reduce across the 16-lane group
            float s = 0.f, q = 0.f;
#pragma unroll
            for (int ni = 0; ni < 8; ++ni) {
                float v = acc[mi][ni][r];
                s += v; q += v * v;
            }
#pragma unroll
            for (int m = 1; m < 16; m <<= 1) {
                s += __shfl_xor(s, m, 64);
                q += __shfl_xor(q, m, 64);
            }
            const float mean = s * (1.f / 128.f);
            const float var  = q * (1.f / 128.f) - mean * mean;
            const float rstd = rsqrtf(var + 1e-5f);

            const int i = wm * 64 + mi * 16 + g * 4 + r;   // row within 128-row tile
            const int h = h0 + (i >> 6);
            const int w = i & 63;
            const int orow = (2 * h + p1) * 128 + 2 * w + p2;
            float* orp = outp + (size_t)orow * 128;
#pragma unroll
            for (int ni = 0; ni < 8; ++ni) {
                float v = (acc[mi][ni][r] - mean) * rstd;
                orp[ni * 16 + c] = v * gam[ni] + bet[ni];
            }
        }
    }
}

extern "C" void kernel_launch(void* const* d_in, const int* in_sizes, int n_in,
                              void* d_out, int out_size, void* d_ws, size_t ws_size,
                              hipStream_t stream) {
    const float* x1   = (const float*)d_in[0];
    const float* Wg   = (const float*)d_in[1];
    const float* gam  = (const float*)d_in[2];
    const float* bet  = (const float*)d_in[3];
    float* out        = (float*)d_out;
    // 65536 M-rows / 128 per block = 512 blocks
    hipLaunchKernelGGL(fused_expand_ln, dim3(512), dim3(512), 0, stream,
                       x1, Wg, gam, bet, out);
}

// Round 2
// 197.242 us; speedup vs baseline: 1.2201x; 1.2201x over previous
//
#include <hip/hip_runtime.h>

// PatchExpand(dim=256) + rearrange + LayerNorm(128), fused, round 2.
// x1:[16,4096,256]f32  W:[512,256]f32  gamma,beta:[128]f32 -> out:[16,16384,128]f32
// GEMM M=65536 N=512 K=256 in bf16 MFMA; LN fused in epilogue.
// R2: occupancy fix — wave tile 32x128 (acc=64 regs), BM=64, LDS 72 KiB,
//     W pre-converted to bf16 (prep kernel) + staged via global_load_lds width=16.

typedef __attribute__((ext_vector_type(8))) short bf16x8;
typedef __attribute__((ext_vector_type(4))) float f32x4;
typedef __attribute__((ext_vector_type(8))) unsigned short u16x8;

__device__ __forceinline__ unsigned short f2bf(float f) {
    unsigned u = __builtin_bit_cast(unsigned, f);
    u += 0x7fffu + ((u >> 16) & 1u);   // RNE (inputs finite)
    return (unsigned short)(u >> 16);
}

#define GLOAD_LDS16(g, l) __builtin_amdgcn_global_load_lds( \
    (const __attribute__((address_space(1))) unsigned int*)(g), \
    (__attribute__((address_space(3))) unsigned int*)(l), 16, 0, 0)

// ---- prep: W f32[512][256] -> ws bf16 chunks [kc][512][64], 16B-slot XOR-swizzled ----
// element (row, k=kc*64+s*8+j) -> ws byte offset kc*65536 + row*128 + ((s^(row&7))<<4) + j*2
__global__ void prep_w(const float* __restrict__ Wg, unsigned short* __restrict__ ws) {
    int sg = blockIdx.x * 256 + threadIdx.x;   // 16384 slots of 8 elems
    int row = sg >> 5;
    int sl  = sg & 31;
    int kc  = sl >> 3;
    int s   = sl & 7;
    const float4* w4 = reinterpret_cast<const float4*>(Wg + (size_t)row * 256 + kc * 64 + s * 8);
    float4 v0 = w4[0], v1 = w4[1];
    u16x8 o = { f2bf(v0.x), f2bf(v0.y), f2bf(v0.z), f2bf(v0.w),
                f2bf(v1.x), f2bf(v1.y), f2bf(v1.z), f2bf(v1.w) };
    char* dst = (char*)ws + kc * 65536 + row * 128 + ((s ^ (row & 7)) << 4);
    *reinterpret_cast<u16x8*>(dst) = o;
}

// ---- main fused kernel ----
// block: 512 thr = 8 waves, wave grid wm(2: 32 rows) x wn(4: 128-col LN chunk)
// BM=64 rows/block (one h-row), BN=512, Kc=64 (4 chunks)
template <bool WS>
__global__ __launch_bounds__(512, 4)
void fused_expand_ln(const float* __restrict__ x1,
                     const float* __restrict__ Wg,
                     const unsigned short* __restrict__ wbf,
                     const float* __restrict__ gamma,
                     const float* __restrict__ beta,
                     float* __restrict__ out) {
    __shared__ unsigned short Alds[64 * 64];    // 8 KiB, XOR-swizzled
    __shared__ unsigned short Wlds[512 * 64];   // 64 KiB, linear dest (pre-swizzled source)

    const int tid  = threadIdx.x;
    const int l0   = blockIdx.x * 64;
    const int wid  = tid >> 6;
    const int lane = tid & 63;
    const int wm   = wid >> 2;                  // 0..1
    const int wn   = wid & 3;                   // 0..3  (LN chunk / p index)
    const int g    = lane >> 4;                 // 0..3
    const int c    = lane & 15;

    f32x4 acc[2][8];
#pragma unroll
    for (int i = 0; i < 2; ++i)
#pragma unroll
        for (int j = 0; j < 8; ++j) acc[i][j] = (f32x4){0.f, 0.f, 0.f, 0.f};

    for (int kc = 0; kc < 4; ++kc) {
        // stage A: 64 rows x 64 k f32 -> bf16, swizzled. 512 slots, 1/thread.
        {
            int row = tid >> 3, s = tid & 7;
            const float4* a4 = reinterpret_cast<const float4*>(
                x1 + (size_t)(l0 + row) * 256 + kc * 64 + s * 8);
            float4 v0 = a4[0], v1 = a4[1];
            u16x8 o = { f2bf(v0.x), f2bf(v0.y), f2bf(v0.z), f2bf(v0.w),
                        f2bf(v1.x), f2bf(v1.y), f2bf(v1.z), f2bf(v1.w) };
            *reinterpret_cast<u16x8*>((char*)Alds + row * 128 + ((s ^ (row & 7)) << 4)) = o;
        }
        // stage W: 64 KiB contiguous (pre-swizzled) -> linear LDS
        if (WS) {
#pragma unroll
            for (int it = 0; it < 8; ++it) {
                const char* gp = (const char*)wbf + kc * 65536 + (tid + it * 512) * 16;
                char* lp = (char*)Wlds + (tid + it * 512) * 16;
                GLOAD_LDS16(gp, lp);
            }
        } else {
            // fallback (no workspace): convert W f32 in-kernel
#pragma unroll
            for (int j = 0; j < 8; ++j) {
                int fidx = tid + j * 512;       // 4096 slots
                int row = fidx >> 3, s = fidx & 7;
                const float4* w4 = reinterpret_cast<const float4*>(
                    Wg + (size_t)row * 256 + kc * 64 + s * 8);
                float4 v0 = w4[0], v1 = w4[1];
                u16x8 o = { f2bf(v0.x), f2bf(v0.y), f2bf(v0.z), f2bf(v0.w),
                            f2bf(v1.x), f2bf(v1.y), f2bf(v1.z), f2bf(v1.w) };
                *reinterpret_cast<u16x8*>((char*)Wlds + row * 128 + ((s ^ (row & 7)) << 4)) = o;
            }
        }
        __syncthreads();

#pragma unroll
        for (int ks = 0; ks < 2; ++ks) {
            const int sA = ks * 4 + g;
            bf16x8 a[2];
#pragma unroll
            for (int mi = 0; mi < 2; ++mi) {
                int ra = wm * 32 + mi * 16 + c;
                a[mi] = *reinterpret_cast<const bf16x8*>(
                    (const char*)Alds + ra * 128 + ((sA ^ (ra & 7)) << 4));
            }
#pragma unroll
            for (int ni = 0; ni < 8; ++ni) {
                int rb = wn * 128 + ni * 16 + c;
                bf16x8 b = *reinterpret_cast<const bf16x8*>(
                    (const char*)Wlds + rb * 128 + ((sA ^ (rb & 7)) << 4));
                acc[0][ni] = __builtin_amdgcn_mfma_f32_16x16x32_bf16(a[0], b, acc[0][ni], 0, 0, 0);
                acc[1][ni] = __builtin_amdgcn_mfma_f32_16x16x32_bf16(a[1], b, acc[1][ni], 0, 0, 0);
            }
        }
        __syncthreads();
    }

    // ---- fused epilogue: LN over each 128-col chunk, scattered write ----
    const int b  = l0 >> 12;
    const int h  = (l0 & 4095) >> 6;            // block covers one full h-row (w = 0..63)
    const int p1 = wn >> 1, p2 = wn & 1;

    float gam[8], bet[8];
#pragma unroll
    for (int ni = 0; ni < 8; ++ni) {
        gam[ni] = gamma[ni * 16 + c];
        bet[ni] = beta[ni * 16 + c];
    }

    float* outp = out + (size_t)b * (16384 * 128) + (size_t)(2 * h + p1) * (128 * 128);

#pragma unroll
    for (int mi = 0; mi < 2; ++mi) {
#pragma unroll
        for (int r = 0; r < 4; ++r) {
            float s = 0.f, q = 0.f;
#pragma unroll
            for (int ni = 0; ni < 8; ++ni) {
                float v = acc[mi][ni][r];
                s += v; q += v * v;
            }
#pragma unroll
            for (int m = 1; m < 16; m <<= 1) {
                s += __shfl_xor(s, m, 64);
                q += __shfl_xor(q, m, 64);
            }
            const float mean = s * (1.f / 128.f);
            const float var  = q * (1.f / 128.f) - mean * mean;
            const float rstd = rsqrtf(var + 1e-5f);

            const int w = wm * 32 + mi * 16 + g * 4 + r;     // 0..63
            float* orp = outp + (size_t)(2 * w + p2) * 128;
#pragma unroll
            for (int ni = 0; ni < 8; ++ni) {
                float v = (acc[mi][ni][r] - mean) * rstd;
                orp[ni * 16 + c] = v * gam[ni] + bet[ni];
            }
        }
    }
}

extern "C" void kernel_launch(void* const* d_in, const int* in_sizes, int n_in,
                              void* d_out, int out_size, void* d_ws, size_t ws_size,
                              hipStream_t stream) {
    const float* x1  = (const float*)d_in[0];
    const float* Wg  = (const float*)d_in[1];
    const float* gam = (const float*)d_in[2];
    const float* bet = (const float*)d_in[3];
    float* out       = (float*)d_out;

    if (ws_size >= 262144) {
        unsigned short* wbf = (unsigned short*)d_ws;
        hipLaunchKernelGGL(prep_w, dim3(64), dim3(256), 0, stream, Wg, wbf);
        hipLaunchKernelGGL((fused_expand_ln<true>), dim3(1024), dim3(512), 0, stream,
                           x1, Wg, wbf, gam, bet, out);
    } else {
        hipLaunchKernelGGL((fused_expand_ln<false>), dim3(1024), dim3(512), 0, stream,
                           x1, Wg, nullptr, gam, bet, out);
    }
}